// Round 5
// baseline (483.807 us; speedup 1.0000x reference)
//
#include <hip/hip_runtime.h>
#include <hip/hip_bf16.h>
#include <cmath>

// Problem: N=64, T=512, D=256, H=256 (all fp32)
//   c   = x @ Wx + b          (N,T,H)  -- big parallel GEMM (phase 1)
//   h_t = tanh(c_t + h_{t-1} @ Wh)     -- sequential scan   (phase 2)
// Output: all h_t, (N,T,H).
//
// Phase 1 writes c directly into d_out; phase 2 updates d_out in place.
//
// Round-5 changes (scan only; GEMM identical to round 4):
//  - W is 64 NAMED SCALARS (no array -> no SROA/alloca ambiguity) and the
//    64 FMAs are four inline-asm blocks of 16 v_fmac_f32 each. Executing
//    the asm requires the 16 W operands to be physically in VGPRs at
//    once, every iteration -> register residency is mandatory, not a
//    hint. Rounds 0-4 (launch_bounds / waves_per_eu / num_vgpr / pin)
//    all left VGPR_Count at 48-60 => W streamed from L2 (~1100 cy/step).
//  - tanhf replaced with inline 1 - 2/(exp(2s)+1) via __expf: removes
//    any possibility of an ocml CALL whose ABI forces caller-saved
//    spills of W around it each iteration.

#define M_TOT 32768   // N*T
#define KDIM  256
#define HDIM  256
#define TSTEPS 512
#define NBATCH 64

// ---------------- Phase 1: c = x @ Wx + b ----------------
// 128x64 tile per block, K-chunks of 32, 256 threads, 8x4 outputs/thread.
// As is stored TRANSPOSED ([k][m]) so the a-fragment is 2 float4 reads.
// Next chunk's global loads are issued before the compute loop (T14).
__global__ __launch_bounds__(256, 2) void xw_gemm(
    const float* __restrict__ x,    // (32768, 256)
    const float* __restrict__ Wx,   // (256, 256)
    const float* __restrict__ bias, // (256)
    float* __restrict__ out)        // (32768, 256)
{
    __shared__ float As[32][132];   // [k][m] (+4 pad; rows 16B-aligned)
    __shared__ float Bs[32][68];    // [k][n] (+4 pad)

    const int tid = threadIdx.x;
    const int tx = tid & 15;        // 0..15 -> 4 output cols each
    const int ty = tid >> 4;        // 0..15 -> 8 output rows each
    const int m0 = blockIdx.x * 128;
    const int n0 = blockIdx.y * 64;

    // Per-thread staging slots (addressing fixed across chunks).
    const int arow = tid >> 1;                 // 0..127 (m)   [2 slots/thread]
    const int ac4a = (tid & 1) << 3;           // 0 or 8       (k, two float4)
    const int brow = tid >> 4;                 // 0..15 (k)    [2 rows/thread]
    const int bc4  = (tid & 15) << 2;          // 0..60 (n)

    float acc[8][4];
#pragma unroll
    for (int i = 0; i < 8; ++i)
#pragma unroll
        for (int j = 0; j < 4; ++j) acc[i][j] = 0.f;

    float4 va0, va1, va2, va3, vb0, vb1;
    // Preload chunk 0.
    {
        const float* xp = &x[(size_t)(m0 + arow) * KDIM];
        va0 = *(const float4*)(xp + ac4a);
        va1 = *(const float4*)(xp + ac4a + 4);
        va2 = *(const float4*)(xp + 16 + ac4a);       // same row, k 16..31
        va3 = *(const float4*)(xp + 16 + ac4a + 4);
        vb0 = *(const float4*)&Wx[(size_t)brow * HDIM + n0 + bc4];
        vb1 = *(const float4*)&Wx[(size_t)(brow + 16) * HDIM + n0 + bc4];
    }

    for (int kc = 0; kc < KDIM; kc += 32) {
        // Write staged registers to LDS (A transposed).
        int k0 = ac4a;
        As[k0 + 0][arow] = va0.x;  As[k0 + 1][arow] = va0.y;
        As[k0 + 2][arow] = va0.z;  As[k0 + 3][arow] = va0.w;
        As[k0 + 4][arow] = va1.x;  As[k0 + 5][arow] = va1.y;
        As[k0 + 6][arow] = va1.z;  As[k0 + 7][arow] = va1.w;
        As[k0 + 16][arow] = va2.x; As[k0 + 17][arow] = va2.y;
        As[k0 + 18][arow] = va2.z; As[k0 + 19][arow] = va2.w;
        As[k0 + 20][arow] = va3.x; As[k0 + 21][arow] = va3.y;
        As[k0 + 22][arow] = va3.z; As[k0 + 23][arow] = va3.w;
        *(float4*)&Bs[brow][bc4]      = vb0;
        *(float4*)&Bs[brow + 16][bc4] = vb1;
        __syncthreads();

        // Issue next chunk's loads now; consumed after compute (latency hidden).
        if (kc + 32 < KDIM) {
            const float* xp = &x[(size_t)(m0 + arow) * KDIM + kc + 32];
            va0 = *(const float4*)(xp + ac4a);
            va1 = *(const float4*)(xp + ac4a + 4);
            va2 = *(const float4*)(xp + 16 + ac4a);
            va3 = *(const float4*)(xp + 16 + ac4a + 4);
            vb0 = *(const float4*)&Wx[(size_t)(kc + 32 + brow) * HDIM + n0 + bc4];
            vb1 = *(const float4*)&Wx[(size_t)(kc + 32 + brow + 16) * HDIM + n0 + bc4];
        }

#pragma unroll
        for (int kk = 0; kk < 32; ++kk) {
            float4 a0 = *(const float4*)&As[kk][ty * 8];
            float4 a1 = *(const float4*)&As[kk][ty * 8 + 4];
            float4 b0 = *(const float4*)&Bs[kk][tx * 4];
            float a[8] = {a0.x, a0.y, a0.z, a0.w, a1.x, a1.y, a1.z, a1.w};
            float b[4] = {b0.x, b0.y, b0.z, b0.w};
#pragma unroll
            for (int i = 0; i < 8; ++i)
#pragma unroll
                for (int j = 0; j < 4; ++j)
                    acc[i][j] += a[i] * b[j];
        }
        __syncthreads();
    }

    float4 bj = *(const float4*)&bias[n0 + tx * 4];
#pragma unroll
    for (int i = 0; i < 8; ++i) {
        float4 v;
        v.x = acc[i][0] + bj.x;
        v.y = acc[i][1] + bj.y;
        v.z = acc[i][2] + bj.z;
        v.w = acc[i][3] + bj.w;
        *(float4*)&out[(size_t)(m0 + ty * 8 + i) * HDIM + n0 + tx * 4] = v;
    }
}

// ---------------- Phase 2: sequential scan ----------------
// One block per batch row. 1024 threads:
//   jq = tid & 63  -> column quad, owns columns 4*jq .. 4*jq+3
//   g  = tid >> 6  -> k-group, owns k in [16*g, 16*g+16)
// W = 64 named scalar floats; FMAs are inline-asm v_fmac_f32 -> W must be
// in VGPRs at every iteration (residency forced structurally).
// h broadcast from LDS; 16-way K partial reduction through LDS.
// c prefetched one step ahead; tanh inlined (no lib call).

// 16 chained v_fmac_f32: ACC += h_k * w_k  (k = 0..15).
// Operands: %0 = ACC, %1-%16 = h0..h15, %17-%32 = w0..w15.
#define FMA16(ACC, W0,W1,W2,W3,W4,W5,W6,W7,W8,W9,W10,W11,W12,W13,W14,W15)   \
    asm("v_fmac_f32 %0, %1, %17\n\t"                                        \
        "v_fmac_f32 %0, %2, %18\n\t"                                        \
        "v_fmac_f32 %0, %3, %19\n\t"                                        \
        "v_fmac_f32 %0, %4, %20\n\t"                                        \
        "v_fmac_f32 %0, %5, %21\n\t"                                        \
        "v_fmac_f32 %0, %6, %22\n\t"                                        \
        "v_fmac_f32 %0, %7, %23\n\t"                                        \
        "v_fmac_f32 %0, %8, %24\n\t"                                        \
        "v_fmac_f32 %0, %9, %25\n\t"                                        \
        "v_fmac_f32 %0, %10, %26\n\t"                                       \
        "v_fmac_f32 %0, %11, %27\n\t"                                       \
        "v_fmac_f32 %0, %12, %28\n\t"                                       \
        "v_fmac_f32 %0, %13, %29\n\t"                                       \
        "v_fmac_f32 %0, %14, %30\n\t"                                       \
        "v_fmac_f32 %0, %15, %31\n\t"                                       \
        "v_fmac_f32 %0, %16, %32\n\t"                                       \
        : "+v"(ACC)                                                         \
        : "v"(h0), "v"(h1), "v"(h2), "v"(h3),                               \
          "v"(h4), "v"(h5), "v"(h6), "v"(h7),                               \
          "v"(h8), "v"(h9), "v"(h10), "v"(h11),                             \
          "v"(h12), "v"(h13), "v"(h14), "v"(h15),                           \
          "v"(W0), "v"(W1), "v"(W2), "v"(W3),                               \
          "v"(W4), "v"(W5), "v"(W6), "v"(W7),                               \
          "v"(W8), "v"(W9), "v"(W10), "v"(W11),                             \
          "v"(W12), "v"(W13), "v"(W14), "v"(W15))

// Load row K of the thread's Wh slice into 4 named scalars.
#define LDW(K)                                                              \
    float4 t##K = *(const float4*)(wp + (K) * HDIM);                        \
    float wA##K = t##K.x, wB##K = t##K.y, wC##K = t##K.z, wD##K = t##K.w;

#define PIN16(P)                                                            \
    asm volatile("" : "+v"(P##0), "+v"(P##1), "+v"(P##2), "+v"(P##3),       \
                      "+v"(P##4), "+v"(P##5), "+v"(P##6), "+v"(P##7),       \
                      "+v"(P##8), "+v"(P##9), "+v"(P##10), "+v"(P##11),     \
                      "+v"(P##12), "+v"(P##13), "+v"(P##14), "+v"(P##15))

__global__ __launch_bounds__(1024)
__attribute__((amdgpu_waves_per_eu(4, 4)))
void rnn_scan(
    const float* __restrict__ h0v,  // (64, 256)
    const float* __restrict__ Wh,   // (256, 256)
    float* __restrict__ out)        // (64, 512, 256), holds c; overwritten with h
{
    const int r   = blockIdx.x;     // batch row
    const int tid = threadIdx.x;
    const int jq  = tid & 63;       // column quad index
    const int g   = tid >> 6;       // k-group (0..15)
    const int j0  = jq << 2;        // first owned column

    __shared__ float h[256];
    __shared__ float red[16][256];  // [k-group][column] partials

    // Persistent W tile as 64 named scalars:
    //   wA_k/wB_k/wC_k/wD_k = Wh[16g+k][j0 + 0/1/2/3]
    const float* wp = Wh + (size_t)(g * 16) * HDIM + j0;
    LDW(0)  LDW(1)  LDW(2)  LDW(3)  LDW(4)  LDW(5)  LDW(6)  LDW(7)
    LDW(8)  LDW(9)  LDW(10) LDW(11) LDW(12) LDW(13) LDW(14) LDW(15)
    PIN16(wA); PIN16(wB); PIN16(wC); PIN16(wD);

    if (tid < 256) h[tid] = h0v[(size_t)r * HDIM + tid];

    float* outr = out + (size_t)r * TSTEPS * HDIM;

    // Prefetch c_0 a full step early.
    float c_next = 0.f;
    if (g < 4) c_next = outr[tid];   // tid<256 <=> g<4 (wave-uniform branch)

    __syncthreads();

    for (int t = 0; t < TSTEPS; ++t) {
        float c = c_next;
        // Prefetch c_{t+1}: a full step (~1000 cy) to cover L2/L3/HBM.
        if (g < 4) {
            int tn = (t + 1 < TSTEPS) ? (t + 1) : t;   // clamp; value unused at t=511
            c_next = outr[(size_t)tn * HDIM + tid];
        }

        // h fragment: 16 broadcast values for this k-group.
        const float4* hv = (const float4*)(h + (g << 4));
        float4 ha = hv[0], hb = hv[1], hc = hv[2], hd = hv[3];
        float h0 = ha.x, h1 = ha.y, h2 = ha.z, h3 = ha.w;
        float h4 = hb.x, h5 = hb.y, h6 = hb.z, h7 = hb.w;
        float h8 = hc.x, h9 = hc.y, h10 = hc.z, h11 = hc.w;
        float h12 = hd.x, h13 = hd.y, h14 = hd.z, h15 = hd.w;

        // acc[q] = sum_k h_k * Wh[16g+k][j0+q], forced-register FMAs.
        float a0 = 0.f, a1 = 0.f, a2 = 0.f, a3 = 0.f;
        FMA16(a0, wA0,wA1,wA2,wA3,wA4,wA5,wA6,wA7,wA8,wA9,wA10,wA11,wA12,wA13,wA14,wA15);
        FMA16(a1, wB0,wB1,wB2,wB3,wB4,wB5,wB6,wB7,wB8,wB9,wB10,wB11,wB12,wB13,wB14,wB15);
        FMA16(a2, wC0,wC1,wC2,wC3,wC4,wC5,wC6,wC7,wC8,wC9,wC10,wC11,wC12,wC13,wC14,wC15);
        FMA16(a3, wD0,wD1,wD2,wD3,wD4,wD5,wD6,wD7,wD8,wD9,wD10,wD11,wD12,wD13,wD14,wD15);

        float4 accv; accv.x = a0; accv.y = a1; accv.z = a2; accv.w = a3;
        *(float4*)&red[g][j0] = accv;  // conflict-free: consecutive float4/lane
        __syncthreads();

        if (tid < 256) {
            // Sum the 16 k-group partials for column tid.
            float s0 = red[0][tid] + red[1][tid];
            float s1 = red[2][tid] + red[3][tid];
            float s2 = red[4][tid] + red[5][tid];
            float s3 = red[6][tid] + red[7][tid];
            float s4 = red[8][tid] + red[9][tid];
            float s5 = red[10][tid] + red[11][tid];
            float s6 = red[12][tid] + red[13][tid];
            float s7 = red[14][tid] + red[15][tid];
            float s  = (((s0 + s1) + (s2 + s3)) + ((s4 + s5) + (s6 + s7))) + c;
            // Inline tanh: 1 - 2/(e^{2s}+1). Exact at +/-inf; no lib call.
            float e  = __expf(2.f * s);
            float hn = 1.f - 2.f / (e + 1.f);
            outr[(size_t)t * HDIM + tid] = hn;  // in-place: c was read above
            h[tid] = hn;                        // safe: all FMA reads done (barrier)
        }
        __syncthreads();   // next step's FMA must see updated h
    }
}

extern "C" void kernel_launch(void* const* d_in, const int* in_sizes, int n_in,
                              void* d_out, int out_size, void* d_ws, size_t ws_size,
                              hipStream_t stream) {
    const float* x  = (const float*)d_in[0];   // (64,512,256)
    const float* h0 = (const float*)d_in[1];   // (64,256)
    const float* Wx = (const float*)d_in[2];   // (256,256)
    const float* Wh = (const float*)d_in[3];   // (256,256)
    const float* b  = (const float*)d_in[4];   // (256)
    float* out = (float*)d_out;                // (64,512,256)

    // Phase 1: input projection into d_out.
    dim3 g1(M_TOT / 128, HDIM / 64);
    xw_gemm<<<g1, 256, 0, stream>>>(x, Wx, b, out);

    // Phase 2: sequential scan, in place.
    rnn_scan<<<NBATCH, 1024, 0, stream>>>(h0, Wh, out);
}

// Round 6
// 462.100 us; speedup vs baseline: 1.0470x; 1.0470x over previous
//
#include <hip/hip_runtime.h>
#include <hip/hip_bf16.h>
#include <cmath>

// Problem: N=64, T=512, D=256, H=256 (all fp32)
//   c   = x @ Wx + b          (N,T,H)  -- parallel GEMM
//   h_t = tanh(c_t + h_{t-1} @ Wh)     -- sequential scan
// Output: all h_t, (N,T,H).
//
// Round-6: FUSE gemm+scan into ONE kernel (producer/consumer via d_ws flags)
// so the ~120us GEMM hides under the ~356us scan.
//  - blocks 0..63: scan (R5 body unchanged: asm-FMA, inline tanh), gated
//    per 64-step chunk on flags[r][ch].
//  - blocks 64..575: GEMM tiles 64m x 256n; tile (r,ch) = blockIdx 64+ch*64+r,
//    ch-major so chunk-0 tiles dispatch first. After stores: __syncthreads,
//    then tid0 release-agent atomicAdd on flags[r][ch].
//  - Consumer: tid0 relaxed-spin + one acquire-agent load, then syncthreads.
//    GEMM blocks never wait -> deadlock-free under any dispatch order.
//  - Scan L2 Wh-stream stays (R0-R5 proved the allocator always spills W;
//    streaming roofline ~1450cy/step; physical-reg asm is a later round).

#define KDIM  256
#define HDIM  256
#define TSTEPS 512
#define NBATCH 64
#define SCAN_BLOCKS 64
#define CH_STEPS 64            // t-steps per chunk
#define NCH 8                  // chunks per row
#define GEMM_BLOCKS (NCH * NBATCH)   // 512
#define SMEM_BYTES 41984       // max(scan 17408, gemm 8704+33280)

// 16 chained v_fmac_f32: ACC += h_k * w_k  (k = 0..15).
#define FMA16(ACC, W0,W1,W2,W3,W4,W5,W6,W7,W8,W9,W10,W11,W12,W13,W14,W15)   \
    asm("v_fmac_f32 %0, %1, %17\n\t"                                        \
        "v_fmac_f32 %0, %2, %18\n\t"                                        \
        "v_fmac_f32 %0, %3, %19\n\t"                                        \
        "v_fmac_f32 %0, %4, %20\n\t"                                        \
        "v_fmac_f32 %0, %5, %21\n\t"                                        \
        "v_fmac_f32 %0, %6, %22\n\t"                                        \
        "v_fmac_f32 %0, %7, %23\n\t"                                        \
        "v_fmac_f32 %0, %8, %24\n\t"                                        \
        "v_fmac_f32 %0, %9, %25\n\t"                                        \
        "v_fmac_f32 %0, %10, %26\n\t"                                       \
        "v_fmac_f32 %0, %11, %27\n\t"                                       \
        "v_fmac_f32 %0, %12, %28\n\t"                                       \
        "v_fmac_f32 %0, %13, %29\n\t"                                       \
        "v_fmac_f32 %0, %14, %30\n\t"                                       \
        "v_fmac_f32 %0, %15, %31\n\t"                                       \
        "v_fmac_f32 %0, %16, %32\n\t"                                       \
        : "+v"(ACC)                                                         \
        : "v"(h0), "v"(h1), "v"(h2), "v"(h3),                               \
          "v"(h4), "v"(h5), "v"(h6), "v"(h7),                               \
          "v"(h8), "v"(h9), "v"(h10), "v"(h11),                             \
          "v"(h12), "v"(h13), "v"(h14), "v"(h15),                           \
          "v"(W0), "v"(W1), "v"(W2), "v"(W3),                               \
          "v"(W4), "v"(W5), "v"(W6), "v"(W7),                               \
          "v"(W8), "v"(W9), "v"(W10), "v"(W11),                             \
          "v"(W12), "v"(W13), "v"(W14), "v"(W15))

#define LDW(K)                                                              \
    float4 t##K = *(const float4*)(wp + (K) * HDIM);                        \
    float wA##K = t##K.x, wB##K = t##K.y, wC##K = t##K.z, wD##K = t##K.w;

#define PIN16(P)                                                            \
    asm volatile("" : "+v"(P##0), "+v"(P##1), "+v"(P##2), "+v"(P##3),       \
                      "+v"(P##4), "+v"(P##5), "+v"(P##6), "+v"(P##7),       \
                      "+v"(P##8), "+v"(P##9), "+v"(P##10), "+v"(P##11),     \
                      "+v"(P##12), "+v"(P##13), "+v"(P##14), "+v"(P##15))

// mode: 0 = fused (flags valid), 1 = gemm-only (no signal), 2 = scan-only (no wait)
__global__ __launch_bounds__(1024) void fused(
    const float* __restrict__ x,    // (32768, 256)
    const float* __restrict__ h0v,  // (64, 256)
    const float* __restrict__ Wx,   // (256, 256)
    const float* __restrict__ Wh,   // (256, 256)
    const float* __restrict__ bias, // (256)
    float* __restrict__ out,        // (64, 512, 256): c, overwritten by h
    unsigned int* flags,            // (64, 8) in d_ws
    int mode)
{
    __shared__ __align__(16) char smem[SMEM_BYTES];
    const int tid = threadIdx.x;

    if (mode == 1 && blockIdx.x < SCAN_BLOCKS) return;   // gemm-only pass
    const bool is_scan = (mode == 2) || (mode == 0 && blockIdx.x < SCAN_BLOCKS);

    if (!is_scan) {
        // ======================= GEMM: 64m x 256n tile =======================
        float (*As)[68]  = (float(*)[68])smem;            // [k][m] transposed
        float (*Bs)[260] = (float(*)[260])(smem + 8704);  // [k][n]

        const int bm = (int)blockIdx.x - SCAN_BLOCKS;     // 0..511
        const int r  = bm & 63;
        const int ch = bm >> 6;                           // ch-major dispatch
        const int m0 = r * TSTEPS + ch * CH_STEPS;
        const int tx = tid & 63;                          // 4 cols each
        const int ty = tid >> 6;                          // 0..15, 4 rows each

        float acc[4][4];
#pragma unroll
        for (int i = 0; i < 4; ++i)
#pragma unroll
            for (int j = 0; j < 4; ++j) acc[i][j] = 0.f;

        for (int kc = 0; kc < KDIM; kc += 32) {
            if (tid < 512) {                              // stage A transposed
                int arow = tid >> 3;                      // 0..63 (m)
                int ac4  = (tid & 7) << 2;                // 0..28 (k)
                float4 va = *(const float4*)&x[(size_t)(m0 + arow) * KDIM + kc + ac4];
                As[ac4 + 0][arow] = va.x;
                As[ac4 + 1][arow] = va.y;
                As[ac4 + 2][arow] = va.z;
                As[ac4 + 3][arow] = va.w;
            }
            {                                             // stage B (2 rows/thread)
                int brow = tid >> 6;                      // 0..15 (k)
                int bc4  = (tid & 63) << 2;               // 0..252 (n)
                *(float4*)&Bs[brow][bc4] =
                    *(const float4*)&Wx[(size_t)(kc + brow) * HDIM + bc4];
                *(float4*)&Bs[brow + 16][bc4] =
                    *(const float4*)&Wx[(size_t)(kc + brow + 16) * HDIM + bc4];
            }
            __syncthreads();

#pragma unroll
            for (int kk = 0; kk < 32; ++kk) {
                float4 a = *(const float4*)&As[kk][ty * 4];  // wave-uniform (bcast)
                float4 b = *(const float4*)&Bs[kk][tx * 4];
                acc[0][0] += a.x * b.x; acc[0][1] += a.x * b.y;
                acc[0][2] += a.x * b.z; acc[0][3] += a.x * b.w;
                acc[1][0] += a.y * b.x; acc[1][1] += a.y * b.y;
                acc[1][2] += a.y * b.z; acc[1][3] += a.y * b.w;
                acc[2][0] += a.z * b.x; acc[2][1] += a.z * b.y;
                acc[2][2] += a.z * b.z; acc[2][3] += a.z * b.w;
                acc[3][0] += a.w * b.x; acc[3][1] += a.w * b.y;
                acc[3][2] += a.w * b.z; acc[3][3] += a.w * b.w;
            }
            __syncthreads();
        }

        float4 bj = *(const float4*)&bias[tx * 4];
#pragma unroll
        for (int i = 0; i < 4; ++i) {
            float4 v;
            v.x = acc[i][0] + bj.x;
            v.y = acc[i][1] + bj.y;
            v.z = acc[i][2] + bj.z;
            v.w = acc[i][3] + bj.w;
            *(float4*)&out[(size_t)(m0 + ty * 4 + i) * HDIM + tx * 4] = v;
        }

        if (mode == 0) {
            __syncthreads();    // all stores program-ordered before signal (hb)
            if (tid == 0)
                __hip_atomic_fetch_add(&flags[r * NCH + ch], 1u,
                                       __ATOMIC_RELEASE, __HIP_MEMORY_SCOPE_AGENT);
        }
        return;
    }

    // ========================= SCAN (R5 body, chunk-gated) =========================
    float* h = (float*)smem;                          // 256 floats
    float (*red)[256] = (float(*)[256])(smem + 1024); // [16][256] partials

    const int r   = (int)blockIdx.x;
    const int jq  = tid & 63;       // column quad
    const int g   = tid >> 6;       // k-group (0..15)
    const int j0  = jq << 2;

    const float* wp = Wh + (size_t)(g * 16) * HDIM + j0;
    LDW(0)  LDW(1)  LDW(2)  LDW(3)  LDW(4)  LDW(5)  LDW(6)  LDW(7)
    LDW(8)  LDW(9)  LDW(10) LDW(11) LDW(12) LDW(13) LDW(14) LDW(15)
    PIN16(wA); PIN16(wB); PIN16(wC); PIN16(wD);

    if (tid < 256) h[tid] = h0v[(size_t)r * HDIM + tid];

    float* outr = out + (size_t)r * TSTEPS * HDIM;
    __syncthreads();

    float c_next = 0.f;
    for (int ch = 0; ch < NCH; ++ch) {
        if (mode == 0) {
            if (tid == 0) {
                const unsigned int* f = &flags[r * NCH + ch];
                while (__hip_atomic_load(f, __ATOMIC_RELAXED,
                                         __HIP_MEMORY_SCOPE_AGENT) == 0u)
                    __builtin_amdgcn_s_sleep(8);
                (void)__hip_atomic_load(f, __ATOMIC_ACQUIRE,
                                        __HIP_MEMORY_SCOPE_AGENT);
            }
            __syncthreads();    // acquire happens-before everyone's c reads
        }
        if (g < 4) c_next = outr[(size_t)(ch * CH_STEPS) * HDIM + tid];

        for (int tt = 0; tt < CH_STEPS; ++tt) {
            const int t = ch * CH_STEPS + tt;
            float c = c_next;
            if (g < 4 && tt + 1 < CH_STEPS)     // stay inside gated chunk
                c_next = outr[(size_t)(t + 1) * HDIM + tid];

            const float4* hv = (const float4*)(h + (g << 4));
            float4 ha = hv[0], hb = hv[1], hc = hv[2], hd = hv[3];
            float h0 = ha.x, h1 = ha.y, h2 = ha.z, h3 = ha.w;
            float h4 = hb.x, h5 = hb.y, h6 = hb.z, h7 = hb.w;
            float h8 = hc.x, h9 = hc.y, h10 = hc.z, h11 = hc.w;
            float h12 = hd.x, h13 = hd.y, h14 = hd.z, h15 = hd.w;

            float a0 = 0.f, a1 = 0.f, a2 = 0.f, a3 = 0.f;
            FMA16(a0, wA0,wA1,wA2,wA3,wA4,wA5,wA6,wA7,wA8,wA9,wA10,wA11,wA12,wA13,wA14,wA15);
            FMA16(a1, wB0,wB1,wB2,wB3,wB4,wB5,wB6,wB7,wB8,wB9,wB10,wB11,wB12,wB13,wB14,wB15);
            FMA16(a2, wC0,wC1,wC2,wC3,wC4,wC5,wC6,wC7,wC8,wC9,wC10,wC11,wC12,wC13,wC14,wC15);
            FMA16(a3, wD0,wD1,wD2,wD3,wD4,wD5,wD6,wD7,wD8,wD9,wD10,wD11,wD12,wD13,wD14,wD15);

            float4 accv; accv.x = a0; accv.y = a1; accv.z = a2; accv.w = a3;
            *(float4*)&red[g][j0] = accv;
            __syncthreads();

            if (tid < 256) {
                float s0 = red[0][tid] + red[1][tid];
                float s1 = red[2][tid] + red[3][tid];
                float s2 = red[4][tid] + red[5][tid];
                float s3 = red[6][tid] + red[7][tid];
                float s4 = red[8][tid] + red[9][tid];
                float s5 = red[10][tid] + red[11][tid];
                float s6 = red[12][tid] + red[13][tid];
                float s7 = red[14][tid] + red[15][tid];
                float s  = (((s0 + s1) + (s2 + s3)) + ((s4 + s5) + (s6 + s7))) + c;
                float e  = __expf(2.f * s);
                float hn = 1.f - 2.f / (e + 1.f);
                outr[(size_t)t * HDIM + tid] = hn;
                h[tid] = hn;
            }
            __syncthreads();
        }
    }
}

extern "C" void kernel_launch(void* const* d_in, const int* in_sizes, int n_in,
                              void* d_out, int out_size, void* d_ws, size_t ws_size,
                              hipStream_t stream) {
    const float* x  = (const float*)d_in[0];   // (64,512,256)
    const float* h0 = (const float*)d_in[1];   // (64,256)
    const float* Wx = (const float*)d_in[2];   // (256,256)
    const float* Wh = (const float*)d_in[3];   // (256,256)
    const float* b  = (const float*)d_in[4];   // (256)
    float* out = (float*)d_out;                // (64,512,256)

    const size_t flag_bytes = (size_t)NBATCH * NCH * sizeof(unsigned int);
    if (d_ws != nullptr && ws_size >= flag_bytes) {
        unsigned int* flags = (unsigned int*)d_ws;
        hipMemsetAsync(d_ws, 0, flag_bytes, stream);
        fused<<<SCAN_BLOCKS + GEMM_BLOCKS, 1024, 0, stream>>>(
            x, h0, Wx, Wh, b, out, flags, 0);
    } else {
        // Fallback: serialized two-pass (R5 behavior).
        fused<<<SCAN_BLOCKS + GEMM_BLOCKS, 1024, 0, stream>>>(
            x, h0, Wx, Wh, b, out, nullptr, 1);
        fused<<<SCAN_BLOCKS, 1024, 0, stream>>>(
            x, h0, Wx, Wh, b, out, nullptr, 2);
    }
}